// Round 5
// baseline (1949.875 us; speedup 1.0000x reference)
//
#include <hip/hip_runtime.h>
#include <math.h>

// Problem constants (C, HID, etc. are structural; N and E taken from in_sizes)
#define CDIM 64
#define NBES 8

#define SQRT3_F     1.7320508075688772f
#define INV_SQRT3_F 0.57735026918962576f
#define INV_SQRT2_F 0.70710678118654752f
#define INV_AVG_NN  0.0625f

// ---------------------------------------------------------------------------
// h0 init: h0[n,k] = node_embed_W[species[n], k]
__global__ __launch_bounds__(256) void k_init(float* __restrict__ h0,
                                              const int* __restrict__ species,
                                              const float* __restrict__ embedW,
                                              int nnodes) {
    int idx = blockIdx.x * 256 + threadIdx.x;
    if (idx < nnodes * 64) {
        int n = idx >> 6, k = idx & 63;
        h0[idx] = embedW[species[n] * 64 + k];
    }
}

// ---------------------------------------------------------------------------
// lin_up: x0 = h0 @ W0 ; x1[d] = h1[d] @ W1   (h1 stored [N][3][C])
__global__ __launch_bounds__(256) void k_linup(const float* __restrict__ h0,
                                               const float* __restrict__ h1,
                                               const float* __restrict__ W0,
                                               const float* __restrict__ W1,
                                               float* __restrict__ x0,
                                               float* __restrict__ x1,
                                               int nnodes) {
    __shared__ float sh[4][4][64];
    const int w = threadIdx.x >> 6, k = threadIdx.x & 63;
    const int n = blockIdx.x * 4 + w;
    const bool valid = n < nnodes;
    float v0 = valid ? h0[n * 64 + k] : 0.f;
    float v1 = valid ? h1[n * 192 + k] : 0.f;
    float v2 = valid ? h1[n * 192 + 64 + k] : 0.f;
    float v3 = valid ? h1[n * 192 + 128 + k] : 0.f;
    sh[w][0][k] = v0; sh[w][1][k] = v1; sh[w][2][k] = v2; sh[w][3][k] = v3;
    __syncthreads();
    float a0 = 0.f, a1 = 0.f, a2 = 0.f, a3 = 0.f;
    for (int c = 0; c < 64; ++c) {
        float w0 = W0[c * 64 + k], w1 = W1[c * 64 + k];
        a0 = fmaf(sh[w][0][c], w0, a0);
        a1 = fmaf(sh[w][1][c], w1, a1);
        a2 = fmaf(sh[w][2][c], w1, a2);
        a3 = fmaf(sh[w][3][c], w1, a3);
    }
    if (valid) {
        x0[n * 64 + k] = a0;
        x1[n * 192 + k] = a1;
        x1[n * 192 + 64 + k] = a2;
        x1[n * 192 + 128 + k] = a3;
    }
}

// ---------------------------------------------------------------------------
// Edge kernel: 64 edges per 320-thread block.
// P0 geometry -> P1 hid1 -> P2 hid2 -> register-tiled GEMM (tpw) -> messages.
//
// The tp GEMM (sH2[64][64] @ W3[64][320]) is 8x8 register-blocked:
// thread t owns cols [cb8, cb8+8) and edges {i*8+eb}, acc[8][8] in VGPRs.
// Round-4 lesson: with __launch_bounds__(320,4) the allocator capped at 64
// arch VGPRs and spilled ~35 floats/thread to scratch (FETCH +105MB,
// WRITE +270MB, 1.6ms outlier dispatch). (320,2) grants a 256-VGPR budget;
// the kernel needs ~120.
//
// sTP layout [5][16][68]: row stride 68 (=4 mod 32 banks) spreads the
// staging writes across 8 bank-windows (was 16-way conflict at stride 320);
// message-phase reads are consecutive-cc, conflict-free.
//
// LDS union sU (disjoint lifetimes): sH1 (P1->P2) | W3 double-buffer (GEMM)
// | tpw staging (message phases).
__global__ __launch_bounds__(320, 2) void k_edge(
    const float* __restrict__ pos, const int* __restrict__ eidx,
    const float* __restrict__ x0, const float* __restrict__ x1,
    const float* __restrict__ W1, const float* __restrict__ W2,
    const float* __restrict__ W3,
    float* __restrict__ M0, float* __restrict__ M1, int nedges) {
    __shared__ __align__(16) float sFEAT[64][8];
    __shared__ float sY1[64][3];
    __shared__ int sSend[64];
    __shared__ int sRecv[64];
    __shared__ __align__(16) float sH2[64 * 65];  // pad 65: GEMM row-reads spread banks
    __shared__ __align__(16) float sU[5440];      // union: sH1[64][64] | w3[2][8][320] | tp[5][16][68]

    float* const sH1 = sU;
    float* const sW3 = sU;
    float* const sTP = sU;

    const int t = threadIdx.x;
    const int cb8 = (t >> 3) * 8;  // first output col (0..312)
    const int eb = t & 7;          // edge sub-index within each 8-edge stripe
    const int wv = t >> 6;         // wave index == path index p of owned cols
    const int c0 = cb8 & 63;       // channel offset within the path block

    // ---- P0: geometry + radial features (fp64 for accuracy), threads 0..63
    if (t < 64) {
        int e = blockIdx.x * 64 + t;
        int s = 0, r = 0;
        float y0 = 0.f, y1 = 0.f, y2 = 0.f;
        float feats[NBES];
#pragma unroll
        for (int b = 0; b < NBES; ++b) feats[b] = 0.f;
        if (e < nedges) {
            s = eidx[e];
            r = eidx[nedges + e];
            double dx = (double)pos[3 * s + 0] - (double)pos[3 * r + 0];
            double dy = (double)pos[3 * s + 1] - (double)pos[3 * r + 1];
            double dz = (double)pos[3 * s + 2] - (double)pos[3 * r + 2];
            double rr = sqrt(dx * dx + dy * dy + dz * dz);
            if (rr < 1e-6) rr = 1e-6;
            double inv = 1.0 / rr;
            y0 = (float)(1.7320508075688772 * dx * inv);
            y1 = (float)(1.7320508075688772 * dy * inv);
            y2 = (float)(1.7320508075688772 * dz * inv);
            double xx = rr * 0.2;  // r / R_MAX
            double f = 0.0;
            if (xx < 1.0) {
                double x2 = xx * xx, x3 = x2 * xx, x6 = x3 * x3;
                f = 1.0 - 28.0 * x6 + 48.0 * x6 * xx - 21.0 * x6 * x2;
            }
            double pref = 0.63245553203367587 * f * inv;  // sqrt(2/R_MAX)
#pragma unroll
            for (int b = 0; b < NBES; ++b) {
                double arg = (double)(b + 1) * 3.14159265358979324 * rr * 0.2;
                feats[b] = (float)(sin(arg) * pref);
            }
        }
        sSend[t] = s;
        sRecv[t] = r;
        sY1[t][0] = y0; sY1[t][1] = y1; sY1[t][2] = y2;
#pragma unroll
        for (int b = 0; b < NBES; ++b) sFEAT[t][b] = feats[b];
    }
    __syncthreads();

    // ---- P1: hid1 = silu(feat @ W1), threads 0..255 (wave -> 16 edges)
    if (t < 256) {
        const int j = t & 63;
        float w1c[NBES];
#pragma unroll
        for (int b = 0; b < NBES; ++b) w1c[b] = W1[b * 64 + j];
#pragma unroll
        for (int i = 0; i < 16; ++i) {
            int el = wv * 16 + i;
            float acc = 0.f;
#pragma unroll
            for (int b = 0; b < NBES; ++b) acc = fmaf(sFEAT[el][b], w1c[b], acc);
            sH1[el * 64 + j] = acc / (1.0f + expf(-acc));
        }
    }
    __syncthreads();

    // ---- P2: hid2 = silu(hid1 @ W2), written with pad-65 rows
    if (t < 256) {
        const int j = t & 63;
        float w2c[64];
#pragma unroll
        for (int c = 0; c < 64; ++c) w2c[c] = W2[c * 64 + j];
#pragma unroll
        for (int i = 0; i < 16; ++i) {
            int el = wv * 16 + i;
            const float4* row = (const float4*)(&sH1[el * 64]);
            float acc = 0.f;
#pragma unroll
            for (int c4 = 0; c4 < 16; ++c4) {
                float4 v = row[c4];
                acc = fmaf(v.x, w2c[4 * c4 + 0], acc);
                acc = fmaf(v.y, w2c[4 * c4 + 1], acc);
                acc = fmaf(v.z, w2c[4 * c4 + 2], acc);
                acc = fmaf(v.w, w2c[4 * c4 + 3], acc);
            }
            sH2[el * 65 + j] = acc / (1.0f + expf(-acc));
        }
    }
    __syncthreads();  // sH2 ready, sH1 dead -> union region now owned by W3 tiles

    // ---- P3: GEMM  acc[i][j] = sum_k sH2[i*8+eb][k] * W3[k][cb8+j]
    // stage K-tile 0 (rows 0..7 of W3) into buffer 0
    {
#pragma unroll
        for (int q = 0; q < 8; ++q) sW3[q * 320 + t] = W3[q * 320 + t];
    }
    __syncthreads();

    float acc[8][8];
#pragma unroll
    for (int i = 0; i < 8; ++i)
#pragma unroll
        for (int j = 0; j < 8; ++j) acc[i][j] = 0.f;

#pragma unroll
    for (int kt = 0; kt < 8; ++kt) {
        const int cur = kt & 1;
        float stg[8];
        if (kt < 7) {  // issue next tile's global loads early (hide under FMAs)
#pragma unroll
            for (int q = 0; q < 8; ++q)
                stg[q] = W3[(kt + 1) * 2560 + q * 320 + t];
        }
        const float* wb = sW3 + cur * 2560;
#pragma unroll
        for (int kk = 0; kk < 8; ++kk) {
            const int k = kt * 8 + kk;
            float h2v[8];
#pragma unroll
            for (int i = 0; i < 8; ++i) h2v[i] = sH2[(i * 8 + eb) * 65 + k];
            float4 wa = *(const float4*)&wb[kk * 320 + cb8];
            float4 wc = *(const float4*)&wb[kk * 320 + cb8 + 4];
            float w3v[8] = {wa.x, wa.y, wa.z, wa.w, wc.x, wc.y, wc.z, wc.w};
#pragma unroll
            for (int i = 0; i < 8; ++i)
#pragma unroll
                for (int j = 0; j < 8; ++j)
                    acc[i][j] = fmaf(h2v[i], w3v[j], acc[i][j]);
        }
        if (kt < 7) {  // write next tile into the other buffer
#pragma unroll
            for (int q = 0; q < 8; ++q)
                sW3[(cur ^ 1) * 2560 + q * 320 + t] = stg[q];
        }
        __syncthreads();
    }
    // (final barrier above also guards the union hand-off W3 -> sTP)

    // ---- P4: 4 message phases, 16 edges each. Thread stages acc[2g][*]
    // (edge g*16+eb) and acc[2g+1][*] (edge g*16+8+eb) into sTP[p][el][ch].
#pragma unroll
    for (int g = 0; g < 4; ++g) {
        {
            const int rowA = (wv * 16 + eb) * 68 + c0;
            const int rowB = (wv * 16 + 8 + eb) * 68 + c0;
            *(float4*)&sTP[rowA] =
                make_float4(acc[2 * g][0], acc[2 * g][1], acc[2 * g][2], acc[2 * g][3]);
            *(float4*)&sTP[rowA + 4] =
                make_float4(acc[2 * g][4], acc[2 * g][5], acc[2 * g][6], acc[2 * g][7]);
            *(float4*)&sTP[rowB] =
                make_float4(acc[2 * g + 1][0], acc[2 * g + 1][1], acc[2 * g + 1][2], acc[2 * g + 1][3]);
            *(float4*)&sTP[rowB + 4] =
                make_float4(acc[2 * g + 1][4], acc[2 * g + 1][5], acc[2 * g + 1][6], acc[2 * g + 1][7]);
        }
        __syncthreads();  // tpw staged
        // 16 edges x 64 channels = 1024 items over 320 threads
        for (int v = t; v < 1024; v += 320) {
            int i = v >> 6, cc = v & 63;
            int el = g * 16 + i;
            int s = sSend[el], r = sRecv[el];
            float X0 = x0[s * 64 + cc];
            float Xx = x1[s * 192 + cc];
            float Xy = x1[s * 192 + 64 + cc];
            float Xz = x1[s * 192 + 128 + cc];
            float Yx = sY1[el][0], Yy = sY1[el][1], Yz = sY1[el][2];
            float t0 = sTP[(0 * 16 + i) * 68 + cc];
            float t1 = sTP[(1 * 16 + i) * 68 + cc];
            float t2 = sTP[(2 * 16 + i) * 68 + cc];
            float t3 = sTP[(3 * 16 + i) * 68 + cc];
            float t4 = sTP[(4 * 16 + i) * 68 + cc];
            float dotp = Xx * Yx + Xy * Yy + Xz * Yz;
            float m0 = t0 * X0 + t3 * (dotp * INV_SQRT3_F);
            float cx = Xy * Yz - Xz * Yy;
            float cy = Xz * Yx - Xx * Yz;
            float cz = Xx * Yy - Xy * Yx;
            float m1x = t1 * X0 * Yx + t2 * Xx + t4 * (cx * INV_SQRT2_F);
            float m1y = t1 * X0 * Yy + t2 * Xy + t4 * (cy * INV_SQRT2_F);
            float m1z = t1 * X0 * Yz + t2 * Xz + t4 * (cz * INV_SQRT2_F);
            atomicAdd(&M0[r * 64 + cc], m0 * INV_AVG_NN);
            atomicAdd(&M1[r * 192 + cc], m1x * INV_AVG_NN);
            atomicAdd(&M1[r * 192 + 64 + cc], m1y * INV_AVG_NN);
            atomicAdd(&M1[r * 192 + 128 + cc], m1z * INV_AVG_NN);
        }
        __syncthreads();  // reads done before next phase overwrites sTP
    }
}

// ---------------------------------------------------------------------------
// Node update: h = prod_lin( product_basis( lin(M) ) ), in place over M
__global__ __launch_bounds__(256) void k_node(
    float* __restrict__ h0, float* __restrict__ h1,
    const int* __restrict__ species,
    const float* __restrict__ linW0, const float* __restrict__ linW1,
    const float* __restrict__ prodW0, const float* __restrict__ prodW1,
    const float* __restrict__ plinW0, const float* __restrict__ plinW1,
    int nnodes) {
    __shared__ float sh[4][4][64];
    const int w = threadIdx.x >> 6, k = threadIdx.x & 63;
    const int n = blockIdx.x * 4 + w;
    const bool valid = n < nnodes;
    float v0 = valid ? h0[n * 64 + k] : 0.f;
    float v1 = valid ? h1[n * 192 + k] : 0.f;
    float v2 = valid ? h1[n * 192 + 64 + k] : 0.f;
    float v3 = valid ? h1[n * 192 + 128 + k] : 0.f;
    sh[w][0][k] = v0; sh[w][1][k] = v1; sh[w][2][k] = v2; sh[w][3][k] = v3;
    __syncthreads();
    float a0 = 0.f, a1 = 0.f, a2 = 0.f, a3 = 0.f;
    for (int c = 0; c < 64; ++c) {
        float w0 = linW0[c * 64 + k], w1 = linW1[c * 64 + k];
        a0 = fmaf(sh[w][0][c], w0, a0);
        a1 = fmaf(sh[w][1][c], w1, a1);
        a2 = fmaf(sh[w][2][c], w1, a2);
        a3 = fmaf(sh[w][3][c], w1, a3);
    }
    // product basis (elementwise in channel)
    int sp = valid ? species[n] : 0;
    float p00 = prodW0[sp * 192 + k];
    float p01 = prodW0[sp * 192 + 64 + k];
    float p02 = prodW0[sp * 192 + 128 + k];
    float p10 = prodW1[sp * 128 + k];
    float p11 = prodW1[sp * 128 + 64 + k];
    float nsq = a1 * a1 + a2 * a2 + a3 * a3;
    float b0 = p00 * a0 + p01 * (a0 * a0) + p02 * (nsq * INV_SQRT3_F);
    float b1x = p10 * a1 + p11 * (a0 * a1);
    float b1y = p10 * a2 + p11 * (a0 * a2);
    float b1z = p10 * a3 + p11 * (a0 * a3);
    __syncthreads();
    sh[w][0][k] = b0; sh[w][1][k] = b1x; sh[w][2][k] = b1y; sh[w][3][k] = b1z;
    __syncthreads();
    a0 = a1 = a2 = a3 = 0.f;
    for (int c = 0; c < 64; ++c) {
        float w0 = plinW0[c * 64 + k], w1 = plinW1[c * 64 + k];
        a0 = fmaf(sh[w][0][c], w0, a0);
        a1 = fmaf(sh[w][1][c], w1, a1);
        a2 = fmaf(sh[w][2][c], w1, a2);
        a3 = fmaf(sh[w][3][c], w1, a3);
    }
    if (valid) {
        h0[n * 64 + k] = a0;
        h1[n * 192 + k] = a1;
        h1[n * 192 + 64 + k] = a2;
        h1[n * 192 + 128 + k] = a3;
    }
}

// ---------------------------------------------------------------------------
// Output: [N, C, 4] = concat(h0, h1_x, h1_y, h1_z) along last dim
__global__ __launch_bounds__(256) void k_out(const float* __restrict__ h0,
                                             const float* __restrict__ h1,
                                             float4* __restrict__ out,
                                             int nnodes) {
    int idx = blockIdx.x * 256 + threadIdx.x;
    if (idx < nnodes * 64) {
        int n = idx >> 6, c = idx & 63;
        float4 o;
        o.x = h0[idx];
        o.y = h1[n * 192 + c];
        o.z = h1[n * 192 + 64 + c];
        o.w = h1[n * 192 + 128 + c];
        out[idx] = o;
    }
}

// ---------------------------------------------------------------------------
extern "C" void kernel_launch(void* const* d_in, const int* in_sizes, int n_in,
                              void* d_out, int out_size, void* d_ws,
                              size_t ws_size, hipStream_t stream) {
    const float* positions = (const float*)d_in[0];
    const int* species = (const int*)d_in[1];
    const int* eidx = (const int*)d_in[2];
    const float* embedW = (const float*)d_in[3];
    const float* linupW0 = (const float*)d_in[4];
    const float* linupW1 = (const float*)d_in[5];
    const float* mlpW1 = (const float*)d_in[6];
    const float* mlpW2 = (const float*)d_in[7];
    const float* mlpW3 = (const float*)d_in[8];
    const float* linW0 = (const float*)d_in[9];
    const float* linW1 = (const float*)d_in[10];
    const float* prodW0 = (const float*)d_in[11];
    const float* prodW1 = (const float*)d_in[12];
    const float* plinW0 = (const float*)d_in[13];
    const float* plinW1 = (const float*)d_in[14];

    const int nn = in_sizes[0] / 3;   // 25000
    const int ne = in_sizes[2] / 2;   // 400000

    // workspace layout (floats): h0 | h1 | x0 | x1   (M aliases h: h dead
    // once lin_up produced x; node-update reads M row then overwrites it)
    float* h0 = (float*)d_ws;
    float* h1 = h0 + (size_t)nn * 64;
    float* x0 = h1 + (size_t)nn * 192;
    float* x1 = x0 + (size_t)nn * 64;

    const int gridN64 = (nn * 64 + 255) / 256;
    const int gridNode = (nn + 3) / 4;
    const int gridEdge = (ne + 63) / 64;

    hipMemsetAsync(h1, 0, (size_t)nn * 192 * sizeof(float), stream);
    k_init<<<gridN64, 256, 0, stream>>>(h0, species, embedW, nn);

    for (int l = 0; l < 2; ++l) {
        k_linup<<<gridNode, 256, 0, stream>>>(
            h0, h1, linupW0 + l * 4096, linupW1 + l * 4096, x0, x1, nn);
        // zero the scatter accumulators (alias h0/h1)
        hipMemsetAsync(h0, 0, (size_t)nn * 64 * sizeof(float), stream);
        hipMemsetAsync(h1, 0, (size_t)nn * 192 * sizeof(float), stream);
        k_edge<<<gridEdge, 320, 0, stream>>>(
            positions, eidx, x0, x1, mlpW1 + l * 512, mlpW2 + l * 4096,
            mlpW3 + l * 20480, h0, h1, ne);
        k_node<<<gridNode, 256, 0, stream>>>(
            h0, h1, species, linW0 + l * 4096, linW1 + l * 4096,
            prodW0 + l * 768, prodW1 + l * 512, plinW0 + l * 4096,
            plinW1 + l * 4096, nn);
    }
    k_out<<<gridN64, 256, 0, stream>>>(h0, h1, (float4*)d_out, nn);
}

// Round 6
// 1392.599 us; speedup vs baseline: 1.4002x; 1.4002x over previous
//
#include <hip/hip_runtime.h>
#include <math.h>

// Problem constants (C, HID, etc. are structural; N and E taken from in_sizes)
#define CDIM 64
#define NBES 8

#define SQRT3_F     1.7320508075688772f
#define INV_SQRT3_F 0.57735026918962576f
#define INV_SQRT2_F 0.70710678118654752f
#define INV_AVG_NN  0.0625f

__device__ __forceinline__ float silu(float x) {
    return x / (1.0f + expf(-x));
}

// ---------------------------------------------------------------------------
// h0 init: h0[n,k] = node_embed_W[species[n], k]
__global__ __launch_bounds__(256) void k_init(float* __restrict__ h0,
                                              const int* __restrict__ species,
                                              const float* __restrict__ embedW,
                                              int nnodes) {
    int idx = blockIdx.x * 256 + threadIdx.x;
    if (idx < nnodes * 64) {
        int n = idx >> 6, k = idx & 63;
        h0[idx] = embedW[species[n] * 64 + k];
    }
}

// ---------------------------------------------------------------------------
// lin_up: x0 = h0 @ W0 ; x1[d] = h1[d] @ W1   (h1 stored [N][3][C])
__global__ __launch_bounds__(256) void k_linup(const float* __restrict__ h0,
                                               const float* __restrict__ h1,
                                               const float* __restrict__ W0,
                                               const float* __restrict__ W1,
                                               float* __restrict__ x0,
                                               float* __restrict__ x1,
                                               int nnodes) {
    __shared__ float sh[4][4][64];
    const int w = threadIdx.x >> 6, k = threadIdx.x & 63;
    const int n = blockIdx.x * 4 + w;
    const bool valid = n < nnodes;
    float v0 = valid ? h0[n * 64 + k] : 0.f;
    float v1 = valid ? h1[n * 192 + k] : 0.f;
    float v2 = valid ? h1[n * 192 + 64 + k] : 0.f;
    float v3 = valid ? h1[n * 192 + 128 + k] : 0.f;
    sh[w][0][k] = v0; sh[w][1][k] = v1; sh[w][2][k] = v2; sh[w][3][k] = v3;
    __syncthreads();
    float a0 = 0.f, a1 = 0.f, a2 = 0.f, a3 = 0.f;
    for (int c = 0; c < 64; ++c) {
        float w0 = W0[c * 64 + k], w1 = W1[c * 64 + k];
        a0 = fmaf(sh[w][0][c], w0, a0);
        a1 = fmaf(sh[w][1][c], w1, a1);
        a2 = fmaf(sh[w][2][c], w1, a2);
        a3 = fmaf(sh[w][3][c], w1, a3);
    }
    if (valid) {
        x0[n * 64 + k] = a0;
        x1[n * 192 + k] = a1;
        x1[n * 192 + 64 + k] = a2;
        x1[n * 192 + 128 + k] = a3;
    }
}

// ---------------------------------------------------------------------------
// Edge kernel: 64 edges per 320-thread block.
//
// Round-5 post-mortem: every prior version was DS-PIPE-bound (~42K
// ds-cycles/block vs ~13K VALU). This version cuts LDS traffic ~2.5x:
//  - GEMM A-operand (sH2) read as b128 (pad-68 rows: conflict-free,
//    16B-aligned), 8 b128/kt instead of 64 b32.
//  - W3 and W2 are read straight from global (L2-resident, VMEM pipe was
//    idle at 8% HBM) -> no W3 LDS staging, NO barriers in the GEMM loop.
//  - P2 register-tiled 4x4 with sH1 stored transposed [k][edge] (pad 68):
//    A-reads become b128 (64/thread vs 256), W2 from global.
// Barriers/block: ~11 (was ~20). VGPR target ~105 (acc 64 + h 16 + w 8 +
// addressing) so the (320,4) 128-cap holds without the r4 spill.
__global__ __launch_bounds__(320, 4) void k_edge(
    const float* __restrict__ pos, const int* __restrict__ eidx,
    const float* __restrict__ x0, const float* __restrict__ x1,
    const float* __restrict__ W1, const float* __restrict__ W2,
    const float* __restrict__ W3,
    float* __restrict__ M0, float* __restrict__ M1, int nedges) {
    __shared__ __align__(16) float sFEAT[64][8];
    __shared__ float sY1[64][3];
    __shared__ int sSend[64];
    __shared__ int sRecv[64];
    __shared__ __align__(16) float sH2[64 * 68];  // pad 68: b128 rows, banks spread
    __shared__ __align__(16) float sU[5440];      // union: sH1T[64*68] | sTP[5*16*68]

    float* const sH1T = sU;  // [k][edge], stride 68
    float* const sTP = sU;   // [5][16][68]

    const int t = threadIdx.x;
    const int eb = t & 7;          // GEMM: edge sub-index (edges i*8+eb)
    const int cb8 = (t >> 3) * 8;  // GEMM: first owned tpw column (0..312)
    const int wv = t >> 6;         // wave index == path index of owned cols
    const int c0 = cb8 & 63;       // channel offset within path block

    // ---- P0: geometry + radial features (fp64 for accuracy), threads 0..63
    if (t < 64) {
        int e = blockIdx.x * 64 + t;
        int s = 0, r = 0;
        float y0 = 0.f, y1 = 0.f, y2 = 0.f;
        float feats[NBES];
#pragma unroll
        for (int b = 0; b < NBES; ++b) feats[b] = 0.f;
        if (e < nedges) {
            s = eidx[e];
            r = eidx[nedges + e];
            double dx = (double)pos[3 * s + 0] - (double)pos[3 * r + 0];
            double dy = (double)pos[3 * s + 1] - (double)pos[3 * r + 1];
            double dz = (double)pos[3 * s + 2] - (double)pos[3 * r + 2];
            double rr = sqrt(dx * dx + dy * dy + dz * dz);
            if (rr < 1e-6) rr = 1e-6;
            double inv = 1.0 / rr;
            y0 = (float)(1.7320508075688772 * dx * inv);
            y1 = (float)(1.7320508075688772 * dy * inv);
            y2 = (float)(1.7320508075688772 * dz * inv);
            double xx = rr * 0.2;  // r / R_MAX
            double f = 0.0;
            if (xx < 1.0) {
                double x2 = xx * xx, x3 = x2 * xx, x6 = x3 * x3;
                f = 1.0 - 28.0 * x6 + 48.0 * x6 * xx - 21.0 * x6 * x2;
            }
            double pref = 0.63245553203367587 * f * inv;  // sqrt(2/R_MAX)
#pragma unroll
            for (int b = 0; b < NBES; ++b) {
                double arg = (double)(b + 1) * 3.14159265358979324 * rr * 0.2;
                feats[b] = (float)(sin(arg) * pref);
            }
        }
        sSend[t] = s;
        sRecv[t] = r;
        sY1[t][0] = y0; sY1[t][1] = y1; sY1[t][2] = y2;
#pragma unroll
        for (int b = 0; b < NBES; ++b) sFEAT[t][b] = feats[b];
    }
    __syncthreads();

    // ---- P1: hid1 = silu(feat @ W1) -> sH1T[k][edge] (transposed, stride 68)
    if (t < 256) {
        const int j = t & 63;
        float w1c[NBES];
#pragma unroll
        for (int b = 0; b < NBES; ++b) w1c[b] = W1[b * 64 + j];
#pragma unroll
        for (int i = 0; i < 16; ++i) {
            int el = wv * 16 + i;
            const float4* fr = (const float4*)(&sFEAT[el][0]);  // broadcast reads
            float4 f0 = fr[0], f1 = fr[1];
            float acc = 0.f;
            acc = fmaf(f0.x, w1c[0], acc);
            acc = fmaf(f0.y, w1c[1], acc);
            acc = fmaf(f0.z, w1c[2], acc);
            acc = fmaf(f0.w, w1c[3], acc);
            acc = fmaf(f1.x, w1c[4], acc);
            acc = fmaf(f1.y, w1c[5], acc);
            acc = fmaf(f1.z, w1c[6], acc);
            acc = fmaf(f1.w, w1c[7], acc);
            sH1T[j * 68 + el] = silu(acc);
        }
    }
    __syncthreads();

    // ---- P2: hid2 = silu(hid1 @ W2), 4 edges x 4 cols per thread,
    // A from sH1T (b128), B from global W2 (L1-resident, 16KB).
    if (t < 256) {
        const int eg = t >> 4;         // edge group: edges 4*eg..+4
        const int j4 = (t & 15) * 4;   // col group: cols j4..j4+4
        float a00 = 0.f, a01 = 0.f, a02 = 0.f, a03 = 0.f;
        float a10 = 0.f, a11 = 0.f, a12 = 0.f, a13 = 0.f;
        float a20 = 0.f, a21 = 0.f, a22 = 0.f, a23 = 0.f;
        float a30 = 0.f, a31 = 0.f, a32 = 0.f, a33 = 0.f;
#pragma unroll 4
        for (int k = 0; k < 64; ++k) {
            float4 av = *(const float4*)&sH1T[k * 68 + 4 * eg];
            float4 wv4 = *(const float4*)&W2[k * 64 + j4];
            a00 = fmaf(av.x, wv4.x, a00); a01 = fmaf(av.x, wv4.y, a01);
            a02 = fmaf(av.x, wv4.z, a02); a03 = fmaf(av.x, wv4.w, a03);
            a10 = fmaf(av.y, wv4.x, a10); a11 = fmaf(av.y, wv4.y, a11);
            a12 = fmaf(av.y, wv4.z, a12); a13 = fmaf(av.y, wv4.w, a13);
            a20 = fmaf(av.z, wv4.x, a20); a21 = fmaf(av.z, wv4.y, a21);
            a22 = fmaf(av.z, wv4.z, a22); a23 = fmaf(av.z, wv4.w, a23);
            a30 = fmaf(av.w, wv4.x, a30); a31 = fmaf(av.w, wv4.y, a31);
            a32 = fmaf(av.w, wv4.z, a32); a33 = fmaf(av.w, wv4.w, a33);
        }
        *(float4*)&sH2[(4 * eg + 0) * 68 + j4] =
            make_float4(silu(a00), silu(a01), silu(a02), silu(a03));
        *(float4*)&sH2[(4 * eg + 1) * 68 + j4] =
            make_float4(silu(a10), silu(a11), silu(a12), silu(a13));
        *(float4*)&sH2[(4 * eg + 2) * 68 + j4] =
            make_float4(silu(a20), silu(a21), silu(a22), silu(a23));
        *(float4*)&sH2[(4 * eg + 3) * 68 + j4] =
            make_float4(silu(a30), silu(a31), silu(a32), silu(a33));
    }
    __syncthreads();  // sH2 ready; sH1T dead -> union free for sTP

    // ---- P3: barrier-free GEMM
    // acc[i][j] = sum_k sH2[i*8+eb][k] * W3[k][cb8+j]; W3 via VMEM (L2-hot)
    float acc[8][8];
#pragma unroll
    for (int i = 0; i < 8; ++i)
#pragma unroll
        for (int j = 0; j < 8; ++j) acc[i][j] = 0.f;

#pragma unroll 1
    for (int kt = 0; kt < 16; ++kt) {  // K-step 4
        float4 h[8];
#pragma unroll
        for (int i = 0; i < 8; ++i)
            h[i] = *(const float4*)&sH2[(i * 8 + eb) * 68 + kt * 4];
#pragma unroll
        for (int kk = 0; kk < 4; ++kk) {
            const int k = kt * 4 + kk;
            float4 wa = *(const float4*)&W3[k * 320 + cb8];
            float4 wb = *(const float4*)&W3[k * 320 + cb8 + 4];
#pragma unroll
            for (int i = 0; i < 8; ++i) {
                float hv = (kk == 0) ? h[i].x
                         : (kk == 1) ? h[i].y
                         : (kk == 2) ? h[i].z
                                     : h[i].w;
                acc[i][0] = fmaf(hv, wa.x, acc[i][0]);
                acc[i][1] = fmaf(hv, wa.y, acc[i][1]);
                acc[i][2] = fmaf(hv, wa.z, acc[i][2]);
                acc[i][3] = fmaf(hv, wa.w, acc[i][3]);
                acc[i][4] = fmaf(hv, wb.x, acc[i][4]);
                acc[i][5] = fmaf(hv, wb.y, acc[i][5]);
                acc[i][6] = fmaf(hv, wb.z, acc[i][6]);
                acc[i][7] = fmaf(hv, wb.w, acc[i][7]);
            }
        }
    }

    // ---- P4: 4 message phases, 16 edges each. Thread stages acc[2g][*]
    // (edge g*16+eb) and acc[2g+1][*] (edge g*16+8+eb) into sTP[p][el][ch].
#pragma unroll
    for (int g = 0; g < 4; ++g) {
        {
            const int rowA = (wv * 16 + eb) * 68 + c0;
            const int rowB = (wv * 16 + 8 + eb) * 68 + c0;
            *(float4*)&sTP[rowA] =
                make_float4(acc[2 * g][0], acc[2 * g][1], acc[2 * g][2], acc[2 * g][3]);
            *(float4*)&sTP[rowA + 4] =
                make_float4(acc[2 * g][4], acc[2 * g][5], acc[2 * g][6], acc[2 * g][7]);
            *(float4*)&sTP[rowB] =
                make_float4(acc[2 * g + 1][0], acc[2 * g + 1][1], acc[2 * g + 1][2], acc[2 * g + 1][3]);
            *(float4*)&sTP[rowB + 4] =
                make_float4(acc[2 * g + 1][4], acc[2 * g + 1][5], acc[2 * g + 1][6], acc[2 * g + 1][7]);
        }
        __syncthreads();  // tpw staged
        // 16 edges x 64 channels = 1024 items over 320 threads
        for (int v = t; v < 1024; v += 320) {
            int i = v >> 6, cc = v & 63;
            int el = g * 16 + i;
            int s = sSend[el], r = sRecv[el];
            float X0 = x0[s * 64 + cc];
            float Xx = x1[s * 192 + cc];
            float Xy = x1[s * 192 + 64 + cc];
            float Xz = x1[s * 192 + 128 + cc];
            float Yx = sY1[el][0], Yy = sY1[el][1], Yz = sY1[el][2];
            float t0 = sTP[(0 * 16 + i) * 68 + cc];
            float t1 = sTP[(1 * 16 + i) * 68 + cc];
            float t2 = sTP[(2 * 16 + i) * 68 + cc];
            float t3 = sTP[(3 * 16 + i) * 68 + cc];
            float t4 = sTP[(4 * 16 + i) * 68 + cc];
            float dotp = Xx * Yx + Xy * Yy + Xz * Yz;
            float m0 = t0 * X0 + t3 * (dotp * INV_SQRT3_F);
            float cx = Xy * Yz - Xz * Yy;
            float cy = Xz * Yx - Xx * Yz;
            float cz = Xx * Yy - Xy * Yx;
            float m1x = t1 * X0 * Yx + t2 * Xx + t4 * (cx * INV_SQRT2_F);
            float m1y = t1 * X0 * Yy + t2 * Xy + t4 * (cy * INV_SQRT2_F);
            float m1z = t1 * X0 * Yz + t2 * Xz + t4 * (cz * INV_SQRT2_F);
            atomicAdd(&M0[r * 64 + cc], m0 * INV_AVG_NN);
            atomicAdd(&M1[r * 192 + cc], m1x * INV_AVG_NN);
            atomicAdd(&M1[r * 192 + 64 + cc], m1y * INV_AVG_NN);
            atomicAdd(&M1[r * 192 + 128 + cc], m1z * INV_AVG_NN);
        }
        __syncthreads();  // reads done before next phase overwrites sTP
    }
}

// ---------------------------------------------------------------------------
// Node update: h = prod_lin( product_basis( lin(M) ) ), in place over M
__global__ __launch_bounds__(256) void k_node(
    float* __restrict__ h0, float* __restrict__ h1,
    const int* __restrict__ species,
    const float* __restrict__ linW0, const float* __restrict__ linW1,
    const float* __restrict__ prodW0, const float* __restrict__ prodW1,
    const float* __restrict__ plinW0, const float* __restrict__ plinW1,
    int nnodes) {
    __shared__ float sh[4][4][64];
    const int w = threadIdx.x >> 6, k = threadIdx.x & 63;
    const int n = blockIdx.x * 4 + w;
    const bool valid = n < nnodes;
    float v0 = valid ? h0[n * 64 + k] : 0.f;
    float v1 = valid ? h1[n * 192 + k] : 0.f;
    float v2 = valid ? h1[n * 192 + 64 + k] : 0.f;
    float v3 = valid ? h1[n * 192 + 128 + k] : 0.f;
    sh[w][0][k] = v0; sh[w][1][k] = v1; sh[w][2][k] = v2; sh[w][3][k] = v3;
    __syncthreads();
    float a0 = 0.f, a1 = 0.f, a2 = 0.f, a3 = 0.f;
    for (int c = 0; c < 64; ++c) {
        float w0 = linW0[c * 64 + k], w1 = linW1[c * 64 + k];
        a0 = fmaf(sh[w][0][c], w0, a0);
        a1 = fmaf(sh[w][1][c], w1, a1);
        a2 = fmaf(sh[w][2][c], w1, a2);
        a3 = fmaf(sh[w][3][c], w1, a3);
    }
    // product basis (elementwise in channel)
    int sp = valid ? species[n] : 0;
    float p00 = prodW0[sp * 192 + k];
    float p01 = prodW0[sp * 192 + 64 + k];
    float p02 = prodW0[sp * 192 + 128 + k];
    float p10 = prodW1[sp * 128 + k];
    float p11 = prodW1[sp * 128 + 64 + k];
    float nsq = a1 * a1 + a2 * a2 + a3 * a3;
    float b0 = p00 * a0 + p01 * (a0 * a0) + p02 * (nsq * INV_SQRT3_F);
    float b1x = p10 * a1 + p11 * (a0 * a1);
    float b1y = p10 * a2 + p11 * (a0 * a2);
    float b1z = p10 * a3 + p11 * (a0 * a3);
    __syncthreads();
    sh[w][0][k] = b0; sh[w][1][k] = b1x; sh[w][2][k] = b1y; sh[w][3][k] = b1z;
    __syncthreads();
    a0 = a1 = a2 = a3 = 0.f;
    for (int c = 0; c < 64; ++c) {
        float w0 = plinW0[c * 64 + k], w1 = plinW1[c * 64 + k];
        a0 = fmaf(sh[w][0][c], w0, a0);
        a1 = fmaf(sh[w][1][c], w1, a1);
        a2 = fmaf(sh[w][2][c], w1, a2);
        a3 = fmaf(sh[w][3][c], w1, a3);
    }
    if (valid) {
        h0[n * 64 + k] = a0;
        h1[n * 192 + k] = a1;
        h1[n * 192 + 64 + k] = a2;
        h1[n * 192 + 128 + k] = a3;
    }
}

// ---------------------------------------------------------------------------
// Output: [N, C, 4] = concat(h0, h1_x, h1_y, h1_z) along last dim
__global__ __launch_bounds__(256) void k_out(const float* __restrict__ h0,
                                             const float* __restrict__ h1,
                                             float4* __restrict__ out,
                                             int nnodes) {
    int idx = blockIdx.x * 256 + threadIdx.x;
    if (idx < nnodes * 64) {
        int n = idx >> 6, c = idx & 63;
        float4 o;
        o.x = h0[idx];
        o.y = h1[n * 192 + c];
        o.z = h1[n * 192 + 64 + c];
        o.w = h1[n * 192 + 128 + c];
        out[idx] = o;
    }
}

// ---------------------------------------------------------------------------
extern "C" void kernel_launch(void* const* d_in, const int* in_sizes, int n_in,
                              void* d_out, int out_size, void* d_ws,
                              size_t ws_size, hipStream_t stream) {
    const float* positions = (const float*)d_in[0];
    const int* species = (const int*)d_in[1];
    const int* eidx = (const int*)d_in[2];
    const float* embedW = (const float*)d_in[3];
    const float* linupW0 = (const float*)d_in[4];
    const float* linupW1 = (const float*)d_in[5];
    const float* mlpW1 = (const float*)d_in[6];
    const float* mlpW2 = (const float*)d_in[7];
    const float* mlpW3 = (const float*)d_in[8];
    const float* linW0 = (const float*)d_in[9];
    const float* linW1 = (const float*)d_in[10];
    const float* prodW0 = (const float*)d_in[11];
    const float* prodW1 = (const float*)d_in[12];
    const float* plinW0 = (const float*)d_in[13];
    const float* plinW1 = (const float*)d_in[14];

    const int nn = in_sizes[0] / 3;   // 25000
    const int ne = in_sizes[2] / 2;   // 400000

    // workspace layout (floats): h0 | h1 | x0 | x1   (M aliases h: h dead
    // once lin_up produced x; node-update reads M row then overwrites it)
    float* h0 = (float*)d_ws;
    float* h1 = h0 + (size_t)nn * 64;
    float* x0 = h1 + (size_t)nn * 192;
    float* x1 = x0 + (size_t)nn * 64;

    const int gridN64 = (nn * 64 + 255) / 256;
    const int gridNode = (nn + 3) / 4;
    const int gridEdge = (ne + 63) / 64;

    hipMemsetAsync(h1, 0, (size_t)nn * 192 * sizeof(float), stream);
    k_init<<<gridN64, 256, 0, stream>>>(h0, species, embedW, nn);

    for (int l = 0; l < 2; ++l) {
        k_linup<<<gridNode, 256, 0, stream>>>(
            h0, h1, linupW0 + l * 4096, linupW1 + l * 4096, x0, x1, nn);
        // zero the scatter accumulators (alias h0/h1)
        hipMemsetAsync(h0, 0, (size_t)nn * 64 * sizeof(float), stream);
        hipMemsetAsync(h1, 0, (size_t)nn * 192 * sizeof(float), stream);
        k_edge<<<gridEdge, 320, 0, stream>>>(
            positions, eidx, x0, x1, mlpW1 + l * 512, mlpW2 + l * 4096,
            mlpW3 + l * 20480, h0, h1, ne);
        k_node<<<gridNode, 256, 0, stream>>>(
            h0, h1, species, linW0 + l * 4096, linW1 + l * 4096,
            prodW0 + l * 768, prodW1 + l * 512, plinW0 + l * 4096,
            plinW1 + l * 4096, nn);
    }
    k_out<<<gridN64, 256, 0, stream>>>(h0, h1, (float4*)d_out, nn);
}